// Round 11
// baseline (1203.801 us; speedup 1.0000x reference)
//
#include <hip/hip_runtime.h>
#include <math.h>

#define NPART 64
#define TILE_F 16

typedef unsigned short u16;
typedef __attribute__((ext_vector_type(8))) short short8;
typedef __attribute__((ext_vector_type(4))) float f32x4;

__device__ __forceinline__ float relu_(float v){ return fmaxf(v, 0.f); }

__device__ __forceinline__ u16 f2bf(float x){
  unsigned u = __float_as_uint(x);
  u = (u + 0x7fffu + ((u >> 16) & 1u)) >> 16;
  return (u16)u;
}

static __device__ __forceinline__ f32x4 mfma_bf16(short8 a, short8 b, f32x4 c){
  asm("v_mfma_f32_16x16x32_bf16 %0, %1, %2, %0" : "+v"(c) : "v"(a), "v"(b));
  return c;
}

// ---------------------------------------------------------------------------
// MFMA mesh-conv (round-7 verified loop), KSTEP=64, B-slice prefetch,
// BN finalize folded into prologue, optional fused residual epilogue.
// Grid = 8 * CSPLIT * ceil(F/BR): batch in low 3 bits (XCD pinning, r10:
// FETCH 111->72MB), column-block in next bits (col-halves share gather
// lines in the same XCD L2). CSPLIT>1 doubles independent blocks/CU to
// hide gather latency (r10: grid-limited at 2.9 blocks/CU, MfmaUtil 11%).
//   out[r,o] = sum_k G[r,k] * W[o,k];  r = b*F+f, k = 4c+j
// ---------------------------------------------------------------------------
template<int CIN,int COUT,int CSPLIT,int WR,int NWR,bool BN,bool STATS,bool RES>
__global__ __launch_bounds__(NWR*(COUT/CSPLIT/64)*64) void mconv_kernel(
    const float* __restrict__ xin, const int* __restrict__ nbr,
    const u16* __restrict__ wbf,
    const float* __restrict__ ps_in, const float* __restrict__ gamma,
    const float* __restrict__ beta, const float* __restrict__ res,
    float* __restrict__ out, float* __restrict__ psum,
    int F, float invN)
{
  constexpr int CW  = COUT/CSPLIT;    // columns per block
  constexpr int nWc = CW/64;
  constexpr int T   = NWR*nWc*64;
  constexpr int BR  = NWR*WR;
  constexpr int K   = 4*CIN;
  constexpr int NSTEP = CIN/16;       // 16 channels (64 k) per step
  constexpr int ITEMS = (BR*4)/T;     // gather work items per thread
  constexpr int NRF   = WR/16;        // row fragments per wave

  __shared__ __align__(16) u16 Gs[2][BR*64];
  __shared__ float ls[STATS?CW:1], lq[STATS?CW:1];
  __shared__ float aS[BN?CIN:1], dS[BN?CIN:1];

  const int t=threadIdx.x, lane=t&63, wid=t>>6;
  const int wm=wid/nWc, wc=wid%nWc;
  const int l15=lane&15, kq=lane>>4;

  const int batch = blockIdx.x & 7;          // XCD-locality: one batch per XCD
  const int rest  = blockIdx.x >> 3;
  const int cblk  = rest % CSPLIT;           // column block (same XCD as row mate)
  const int row0  = (rest / CSPLIT) * BR;
  const int col0  = cblk*CW;

  if (BN){
    for (int c=t;c<CIN;c+=T){
      float s=0.f,q=0.f;
      #pragma unroll 4
      for (int p=0;p<NPART;p++){ s+=ps_in[p*256+c]; q+=ps_in[(NPART+p)*256+c]; }
      float m=s*invN, v=q*invN-m*m;
      float ai=gamma[c]*rsqrtf(v+1e-5f);
      aS[c]=ai; dS[c]=beta[c]-m*ai;
    }
  }
  if (STATS){ for (int i=t;i<CW;i+=T){ ls[i]=0.f; lq[i]=0.f; } }
  __syncthreads();

  // ---- gather pointers (fixed rows/channel-quads per thread) ----
  const float *P0[ITEMS],*P1[ITEMS],*P2[ITEMS],*P3[ITEMS];
  #pragma unroll
  for (int i=0;i<ITEMS;i++){
    int idx=i*T+t, gr=idx>>2, c4q=idx&3;
    int f=row0+gr;
    if (f>=F) f=F-1;                      // clamp tail rows (outputs discarded)
    int i1=nbr[f*3+0], i2=nbr[f*3+1], i3=nbr[f*3+2];
    const float* xb=xin+(size_t)batch*F*CIN+c4q*4;
    P0[i]=xb+(size_t)f *CIN; P1[i]=xb+(size_t)i1*CIN;
    P2[i]=xb+(size_t)i2*CIN; P3[i]=xb+(size_t)i3*CIN;
  }

  const u16* wp = wbf + (size_t)(col0 + wc*64 + l15)*K + kq*8;
  auto BLD=[&](int cg,int j)->short8{
    return *(const short8*)(wp + (size_t)cg*16*K + (size_t)j*32);
  };
  auto ADS=[&](int pb,int rr,int h)->short8{
    int r=wm*WR+rr*16+l15;
    int sl=h*4+kq;
    return *(const short8*)&Gs[pb][(size_t)r*64 + (size_t)((sl^(r&7))*8)];
  };
  auto GLD=[&](int s,float4 (&g)[ITEMS][4]){
    #pragma unroll
    for (int i=0;i<ITEMS;i++){
      g[i][0]=*(const float4*)(P0[i]+s*16);
      g[i][1]=*(const float4*)(P1[i]+s*16);
      g[i][2]=*(const float4*)(P2[i]+s*16);
      g[i][3]=*(const float4*)(P3[i]+s*16);
    }
  };
  auto BLDW=[&](int pb,int s,float4 (&g)[ITEMS][4]){
    #pragma unroll
    for (int i=0;i<ITEMS;i++){
      int idx=i*T+t, gr=idx>>2, c4q=idx&3;
      float4 S=g[i][0],N1=g[i][1],N2=g[i][2],N3=g[i][3];
      if (BN){
        float4 a4=*(const float4*)&aS[s*16+c4q*4];
        float4 d4=*(const float4*)&dS[s*16+c4q*4];
        S.x =fmaf(relu_(S.x ),a4.x,d4.x); S.y =fmaf(relu_(S.y ),a4.y,d4.y);
        S.z =fmaf(relu_(S.z ),a4.z,d4.z); S.w =fmaf(relu_(S.w ),a4.w,d4.w);
        N1.x=fmaf(relu_(N1.x),a4.x,d4.x); N1.y=fmaf(relu_(N1.y),a4.y,d4.y);
        N1.z=fmaf(relu_(N1.z),a4.z,d4.z); N1.w=fmaf(relu_(N1.w),a4.w,d4.w);
        N2.x=fmaf(relu_(N2.x),a4.x,d4.x); N2.y=fmaf(relu_(N2.y),a4.y,d4.y);
        N2.z=fmaf(relu_(N2.z),a4.z,d4.z); N2.w=fmaf(relu_(N2.w),a4.w,d4.w);
        N3.x=fmaf(relu_(N3.x),a4.x,d4.x); N3.y=fmaf(relu_(N3.y),a4.y,d4.y);
        N3.z=fmaf(relu_(N3.z),a4.z,d4.z); N3.w=fmaf(relu_(N3.w),a4.w,d4.w);
      }
      short8 lo,hi;
      #define FEAT(dst,i0,sv,av,bv,cv) \
        dst[i0+0]=(short)f2bf(sv); \
        dst[i0+1]=(short)f2bf(av+bv+cv); \
        dst[i0+2]=(short)f2bf(fabsf(av-bv)+fabsf(bv-cv)+fabsf(cv-av)); \
        dst[i0+3]=(short)f2bf(fmaxf(fmaxf(av,bv),cv));
      FEAT(lo,0,S.x,N1.x,N2.x,N3.x)
      FEAT(lo,4,S.y,N1.y,N2.y,N3.y)
      FEAT(hi,0,S.z,N1.z,N2.z,N3.z)
      FEAT(hi,4,S.w,N1.w,N2.w,N3.w)
      #undef FEAT
      u16* rowp=&Gs[pb][(size_t)gr*64];
      *(short8*)&rowp[(size_t)(((2*c4q  )^(gr&7))*8)]=lo;
      *(short8*)&rowp[(size_t)(((2*c4q+1)^(gr&7))*8)]=hi;
    }
  };

  f32x4 acc[NRF][4];
  #pragma unroll
  for (int rr=0;rr<NRF;rr++)
    #pragma unroll
    for (int cg=0;cg<4;cg++){ f32x4 z={0.f,0.f,0.f,0.f}; acc[rr][cg]=z; }

  short8 B0[4],B1[4];
  #pragma unroll
  for (int cg=0;cg<4;cg++) B0[cg]=BLD(cg,0);
  #pragma unroll
  for (int cg=0;cg<4;cg++) B1[cg]=BLD(cg,1);

  { float4 g0[ITEMS][4]; GLD(0,g0); BLDW(0,0,g0); }
  __syncthreads();

  // round-7 verified single-step pipeline (2-deep regressed, r9)
  #pragma unroll 2
  for (int s=0;s<NSTEP;s++){
    const int pb=s&1;
    float4 g[ITEMS][4];
    if (s+1<NSTEP) GLD(s+1,g);               // issue gathers for next step
    short8 A[NRF];
    #pragma unroll
    for (int rr=0;rr<NRF;rr++) A[rr]=ADS(pb,rr,0);
    #pragma unroll
    for (int rr=0;rr<NRF;rr++)
      #pragma unroll
      for (int cg=0;cg<4;cg++) acc[rr][cg]=mfma_bf16(A[rr],B0[cg],acc[rr][cg]);
    if (s+1<NSTEP){
      #pragma unroll
      for (int cg=0;cg<4;cg++) B0[cg]=BLD(cg,2*(s+1));   // prefetch next slice
    }
    #pragma unroll
    for (int rr=0;rr<NRF;rr++) A[rr]=ADS(pb,rr,1);
    #pragma unroll
    for (int rr=0;rr<NRF;rr++)
      #pragma unroll
      for (int cg=0;cg<4;cg++) acc[rr][cg]=mfma_bf16(A[rr],B1[cg],acc[rr][cg]);
    if (s+1<NSTEP){
      #pragma unroll
      for (int cg=0;cg<4;cg++) B1[cg]=BLD(cg,2*(s+1)+1);
      BLDW(pb^1,s+1,g);                      // features -> other buffer
    }
    __syncthreads();
  }

  // ---- epilogue: (optional fused residual+relu) store + relu stats ----
  const size_t bbase=(size_t)batch*F;
  #pragma unroll
  for (int cg=0;cg<4;cg++){
    const int cl=wc*64+cg*16+l15;         // block-local column
    const int col=col0+cl;                // global column
    float rs=0.f,rq=0.f;
    #pragma unroll
    for (int rr=0;rr<NRF;rr++){
      const int r0=row0 + wm*WR + rr*16 + kq*4;
      #pragma unroll
      for (int q=0;q<4;q++){
        int r=r0+q;
        if (r<F){
          size_t idx=(bbase+r)*COUT+col;
          float v=acc[rr][cg][q];
          if (RES){ v += res[idx]; v = relu_(v); }
          out[idx]=v;
          if (STATS){ float rv = RES ? v : relu_(v); rs+=rv; rq+=rv*rv; }
        }
      }
    }
    if (STATS){ atomicAdd(&ls[cl],rs); atomicAdd(&lq[cl],rq); }
  }
  if (STATS){
    __syncthreads();
    const int part=blockIdx.x&(NPART-1);
    for (int i=t;i<CW;i+=T){
      atomicAdd(&psum[(size_t)part*256+col0+i],ls[i]);
      atomicAdd(&psum[(size_t)(NPART+part)*256+col0+i],lq[i]);
    }
  }
}

// ---------------------------------------------------------------------------
// fp32 conv path (tiny 9->64 conv only)
// ---------------------------------------------------------------------------
template<int CIN,int COUT,bool BN,bool STATS>
__global__ __launch_bounds__(256) void conv_kernel(
    const float* __restrict__ xin, const int* __restrict__ nbr,
    const float* __restrict__ Wt, const float* __restrict__ bn_a,
    const float* __restrict__ bn_d,
    float* __restrict__ out, float* __restrict__ psum, int F)
{
  constexpr int K = 4*CIN;
  constexpr int ROWLEN = K + 4;
  __shared__ float Gs[TILE_F][ROWLEN];
  __shared__ int   nI[TILE_F*3];
  __shared__ float ls[STATS?COUT:1];
  __shared__ float lq[STATS?COUT:1];
  const int t = threadIdx.x;
  const int fbase = blockIdx.x*TILE_F;
  const int b = blockIdx.y;
  const float* __restrict__ xb = xin + (size_t)b*F*CIN;

  if (t < TILE_F*3){ int fi=t/3, j=t-fi*3; int fg=fbase+fi; nI[t]=(fg<F)?nbr[fg*3+j]:0; }
  if (STATS){ for (int i=t;i<COUT;i+=256){ ls[i]=0.f; lq[i]=0.f; } }
  __syncthreads();

  for (int idx=t; idx<TILE_F*CIN; idx+=256){
    int fi=idx/CIN, c=idx-fi*CIN;
    int fg=fbase+fi;
    float* dst=&Gs[fi][4*c];
    if (fg<F){
      int i1=nI[fi*3], i2=nI[fi*3+1], i3=nI[fi*3+2];
      float s =xb[(size_t)fg*CIN+c];
      float v1=xb[(size_t)i1*CIN+c];
      float v2=xb[(size_t)i2*CIN+c];
      float v3=xb[(size_t)i3*CIN+c];
      if (BN){ float a=bn_a[c], dd=bn_d[c];
        s=fmaf(relu_(s),a,dd); v1=fmaf(relu_(v1),a,dd);
        v2=fmaf(relu_(v2),a,dd); v3=fmaf(relu_(v3),a,dd); }
      dst[0]=s; dst[1]=v1+v2+v3;
      dst[2]=fabsf(v1-v2)+fabsf(v2-v3)+fabsf(v3-v1);
      dst[3]=fmaxf(fmaxf(v1,v2),v3);
    } else { dst[0]=0.f;dst[1]=0.f;dst[2]=0.f;dst[3]=0.f; }
  }
  __syncthreads();

  constexpr int OQ=COUT/4;
  constexpr int R=256/OQ;
  constexpr int FPT=TILE_F/R;
  const int col=t%OQ, row=t/OQ;
  const int o0=col*4, f0=row*FPT;
  float4 acc[FPT];
  #pragma unroll
  for (int fi=0;fi<FPT;fi++){ acc[fi].x=0.f;acc[fi].y=0.f;acc[fi].z=0.f;acc[fi].w=0.f; }

  for (int k=0;k<K;k+=4){
    float4 w0=*(const float4*)&Wt[(size_t)(k+0)*COUT+o0];
    float4 w1=*(const float4*)&Wt[(size_t)(k+1)*COUT+o0];
    float4 w2=*(const float4*)&Wt[(size_t)(k+2)*COUT+o0];
    float4 w3=*(const float4*)&Wt[(size_t)(k+3)*COUT+o0];
    #pragma unroll
    for (int fi=0;fi<FPT;fi++){
      float4 g=*(const float4*)&Gs[f0+fi][k];
      acc[fi].x=fmaf(g.x,w0.x,fmaf(g.y,w1.x,fmaf(g.z,w2.x,fmaf(g.w,w3.x,acc[fi].x))));
      acc[fi].y=fmaf(g.x,w0.y,fmaf(g.y,w1.y,fmaf(g.z,w2.y,fmaf(g.w,w3.y,acc[fi].y))));
      acc[fi].z=fmaf(g.x,w0.z,fmaf(g.y,w1.z,fmaf(g.z,w2.z,fmaf(g.w,w3.z,acc[fi].z))));
      acc[fi].w=fmaf(g.x,w0.w,fmaf(g.y,w1.w,fmaf(g.z,w2.w,fmaf(g.w,w3.w,acc[fi].w))));
    }
  }

  float4 rs={0,0,0,0}, rq={0,0,0,0};
  #pragma unroll
  for (int fi=0;fi<FPT;fi++){
    int fg=fbase+f0+fi;
    if (fg<F){
      *(float4*)&out[((size_t)b*F+fg)*COUT+o0]=acc[fi];
      if (STATS){
        float rx=relu_(acc[fi].x), ry=relu_(acc[fi].y);
        float rz=relu_(acc[fi].z), rw=relu_(acc[fi].w);
        rs.x+=rx; rs.y+=ry; rs.z+=rz; rs.w+=rw;
        rq.x+=rx*rx; rq.y+=ry*ry; rq.z+=rz*rz; rq.w+=rw*rw;
      }
    }
  }
  if (STATS){
    atomicAdd(&ls[o0+0],rs.x); atomicAdd(&ls[o0+1],rs.y);
    atomicAdd(&ls[o0+2],rs.z); atomicAdd(&ls[o0+3],rs.w);
    atomicAdd(&lq[o0+0],rq.x); atomicAdd(&lq[o0+1],rq.y);
    atomicAdd(&lq[o0+2],rq.z); atomicAdd(&lq[o0+3],rq.w);
    __syncthreads();
    int part=(blockIdx.y*gridDim.x+blockIdx.x)&(NPART-1);
    for (int i=t;i<COUT;i+=256){
      atomicAdd(&psum[(size_t)part*256+i], ls[i]);
      atomicAdd(&psum[(size_t)(NPART+part)*256+i], lq[i]);
    }
  }
}

// pool with folded BN finalize: aS/dS computed from psum partials per block
__global__ __launch_bounds__(256) void pool_kernel(
    const float* __restrict__ z, const int* __restrict__ pl,
    const float* __restrict__ ps_in, const float* __restrict__ gamma,
    const float* __restrict__ beta,
    float* __restrict__ out, int C4, int F, int Fn, int n4, float invN)
{
  __shared__ float aS[256], dS[256];
  const int C=C4*4;
  const int t=threadIdx.x;
  if (t<C){
    float s=0.f,q=0.f;
    #pragma unroll 4
    for (int p=0;p<NPART;p++){ s+=ps_in[p*256+t]; q+=ps_in[(NPART+p)*256+t]; }
    float m=s*invN, v=q*invN-m*m;
    float ai=gamma[t]*rsqrtf(v+1e-5f);
    aS[t]=ai; dS[t]=beta[t]-m*ai;
  }
  __syncthreads();
  for (int i=blockIdx.x*256+t; i<n4; i+=gridDim.x*256){
    int c4=i%C4; int rest=i/C4; int p=rest%Fn; int b=rest/Fn;
    int p0=pl[p*3], p1=pl[p*3+1], p2=pl[p*3+2];
    float4 a4=*(const float4*)&aS[4*c4], d4=*(const float4*)&dS[4*c4];
    float4 v0=*(const float4*)&z[((size_t)b*F+p0)*C+4*c4];
    float4 v1=*(const float4*)&z[((size_t)b*F+p1)*C+4*c4];
    float4 v2=*(const float4*)&z[((size_t)b*F+p2)*C+4*c4];
    float4 r;
    r.x=(relu_(fmaf(v0.x,a4.x,d4.x))+relu_(fmaf(v1.x,a4.x,d4.x))+relu_(fmaf(v2.x,a4.x,d4.x)))*(1.f/3.f);
    r.y=(relu_(fmaf(v0.y,a4.y,d4.y))+relu_(fmaf(v1.y,a4.y,d4.y))+relu_(fmaf(v2.y,a4.y,d4.y)))*(1.f/3.f);
    r.z=(relu_(fmaf(v0.z,a4.z,d4.z))+relu_(fmaf(v1.z,a4.z,d4.z))+relu_(fmaf(v2.z,a4.z,d4.z)))*(1.f/3.f);
    r.w=(relu_(fmaf(v0.w,a4.w,d4.w))+relu_(fmaf(v1.w,a4.w,d4.w))+relu_(fmaf(v2.w,a4.w,d4.w)))*(1.f/3.f);
    *(float4*)&out[((size_t)b*Fn+p)*C+4*c4]=r;
  }
}

__global__ __launch_bounds__(256) void colsum_kernel(
    const float* __restrict__ x, float* __restrict__ bc, int F, int chunk)
{
  int b=blockIdx.y; int f0=blockIdx.x*chunk;
  int c=threadIdx.x;
  int fe=f0+chunk; if (fe>F) fe=F;
  float s=0.f;
  for (int f=f0;f<fe;f++) s+=x[((size_t)b*F+f)*256+c];
  atomicAdd(&bc[b*256+c], s);
}

__global__ __launch_bounds__(256) void head_kernel(
    const float* __restrict__ bc, const float* __restrict__ w1,
    const float* __restrict__ b1, const float* __restrict__ w2,
    const float* __restrict__ b2, float* __restrict__ outp, float invF)
{
  __shared__ float xm[8*256];
  __shared__ float h[8*128];
  int t=threadIdx.x;
  for (int i=t;i<2048;i+=256) xm[i]=bc[i]*invF;
  __syncthreads();
  #pragma unroll
  for (int r=0;r<4;r++){
    int idx=t+r*256; int b=idx>>7, j=idx&127;
    float s=b1[j];
    for (int c=0;c<256;c++) s=fmaf(xm[b*256+c],w1[j*256+c],s);
    h[idx]=relu_(s);
  }
  __syncthreads();
  if (t<8){
    float s=b2[0];
    for (int j=0;j<128;j++) s=fmaf(h[t*128+j],w2[j],s);
    outp[t]=1.f/(1.f+expf(-s));
  }
}

__global__ __launch_bounds__(256) void transpose_in_kernel(
    const float* __restrict__ x, float* __restrict__ xt, int F)
{
  int i=blockIdx.x*256+threadIdx.x;
  int total=8*9*F;
  if (i<total){ int f=i%F; int c=(i/F)%9; int b=i/(9*F);
    xt[((size_t)b*F+f)*9+c]=x[i]; }
}

__global__ __launch_bounds__(256) void transpose_w_kernel(
    const float* __restrict__ w, float* __restrict__ wt, int K, int COUT)
{
  int i=blockIdx.x*256+threadIdx.x;
  if (i<K*COUT){ int o=i/K, k=i-o*K; wt[(size_t)k*COUT+o]=w[i]; }
}

__global__ __launch_bounds__(256) void cvt_bf16_kernel(
    const float* __restrict__ w, u16* __restrict__ o, int n)
{
  int i=blockIdx.x*256+threadIdx.x;
  if (i<n) o[i]=f2bf(w[i]);
}

// ---------------------------------------------------------------------------

template<int CIN,int COUT,int CSPLIT,int WR,int NWR,bool BN,bool STATS,bool RES>
static void launch_mconv(const float* xin, const int* nbr, const u16* wbf,
                         const float* ps_in, const float* gamma, const float* beta,
                         const float* res, float* out, float* ps_out,
                         int F, float invN, hipStream_t stream)
{
  constexpr int T  = NWR*(COUT/CSPLIT/64)*64;
  constexpr int BR = NWR*WR;
  int nb = (F + BR - 1)/BR;
  mconv_kernel<CIN,COUT,CSPLIT,WR,NWR,BN,STATS,RES><<<8*nb*CSPLIT, T, 0, stream>>>(
      xin,nbr,wbf,ps_in,gamma,beta,res,out,ps_out,F,invN);
}

extern "C" void kernel_launch(void* const* d_in, const int* in_sizes, int n_in,
                              void* d_out, int out_size, void* d_ws, size_t ws_size,
                              hipStream_t stream)
{
  const float* x    =(const float*)d_in[0];
  const int*  nbr0  =(const int*)d_in[1];
  const int*  pool0 =(const int*)d_in[2];
  const int*  nbr1  =(const int*)d_in[3];
  const int*  pool1 =(const int*)d_in[4];
  const int*  nbr2  =(const int*)d_in[5];
  const int*  pool2 =(const int*)d_in[6];
  const float* wc0  =(const float*)d_in[7];
  const float* ws0  =(const float*)d_in[8];
  const float* bng0 =(const float*)d_in[9];
  const float* bnb0 =(const float*)d_in[10];
  const float* ng0  =(const float*)d_in[11];
  const float* nb0  =(const float*)d_in[12];
  const float* wc1  =(const float*)d_in[13];
  const float* ws1  =(const float*)d_in[14];
  const float* bng1 =(const float*)d_in[15];
  const float* bnb1 =(const float*)d_in[16];
  const float* ng1  =(const float*)d_in[17];
  const float* nb1  =(const float*)d_in[18];
  const float* wc2  =(const float*)d_in[19];
  const float* ws2  =(const float*)d_in[20];
  const float* bng2 =(const float*)d_in[21];
  const float* bnb2 =(const float*)d_in[22];
  const float* ng2  =(const float*)d_in[23];
  const float* nb2  =(const float*)d_in[24];
  const float* fc1w =(const float*)d_in[25];
  const float* fc1b =(const float*)d_in[26];
  const float* fc2w =(const float*)d_in[27];
  const float* fc2b =(const float*)d_in[28];
  float* outp=(float*)d_out;

  char* base=(char*)d_ws;
  size_t off=0;
  auto alloc=[&](size_t nbytes)->void*{
    void* p=base+off; off=(off+nbytes+255)&~(size_t)255; return p; };

  float* psum0 =(float*)alloc((size_t)12*131072);
  float* bc    =(float*)alloc(8192);
  float* wt_wc0=(float*)alloc((size_t)36*64*4);
  u16*   bws0  =(u16*)alloc((size_t)3*16384*2);
  u16*   bwc1  =(u16*)alloc((size_t)32768*2);
  u16*   bws1  =(u16*)alloc((size_t)3*65536*2);
  u16*   bwc2  =(u16*)alloc((size_t)131072*2);
  u16*   bws2  =(u16*)alloc((size_t)3*262144*2);
  float* xT    =(float*)alloc((size_t)8*12000*9*4);
  float* B0    =(float*)alloc((size_t)49152000);
  float* B1    =(float*)alloc((size_t)49152000);
  float* B2    =(float*)alloc((size_t)49152000);
  if (off>ws_size) return;

  auto PS=[&](int i){ return psum0+(size_t)i*32768; };

  hipMemsetAsync(psum0,0,(size_t)12*131072+8192,stream);

  { int n=8*9*12000; transpose_in_kernel<<<(n+255)/256,256,0,stream>>>(x,xT,12000); }
  { int n=36*64; transpose_w_kernel<<<(n+255)/256,256,0,stream>>>(wc0,wt_wc0,36,64); }
  auto cv=[&](const float* w,u16* o,int n){
    cvt_bf16_kernel<<<(n+255)/256,256,0,stream>>>(w,o,n); };
  cv(ws0,bws0,3*16384);
  cv(wc1,bwc1,32768);
  cv(ws1,bws1,3*65536);
  cv(wc2,bwc2,131072);
  cv(ws2,bws2,3*262144);

  // -------- stage 0: F=12000, 9 -> 64 --------
  {
    const int F=12000; const float invN=1.f/(8.f*F);
    dim3 grid((F+TILE_F-1)/TILE_F, 8);
    conv_kernel<9,64,false,true><<<grid,256,0,stream>>>(xT,nbr0,wt_wc0,nullptr,nullptr,B0,PS(0),F);
    launch_mconv<64,64,1,32,2,true,true ,false>(B0,nbr0,bws0,        PS(0),bng0,     bnb0,     nullptr,B1,PS(1),F,invN,stream);
    launch_mconv<64,64,1,32,2,true,true ,false>(B1,nbr0,bws0+16384,  PS(1),bng0+64,  bnb0+64,  nullptr,B2,PS(2),F,invN,stream);
    // 4th conv: fused residual relu(y + B0) + stats for the outer BN (PS(3))
    launch_mconv<64,64,1,32,2,true,true ,true >(B2,nbr0,bws0+32768,  PS(2),bng0+128, bnb0+128, B0,     B1,PS(3),F,invN,stream);
    int n4p=8*9000*16; int gp=(n4p+255)/256; if (gp>2048) gp=2048;
    pool_kernel<<<gp,256,0,stream>>>(B1,pool0,PS(3),ng0,nb0,B2,16,F,9000,n4p,invN);
  }
  // -------- stage 1: F=9000, 64 -> 128 (CSPLIT=2: 2256 blocks of 128 thr) --------
  {
    const int F=9000; const float invN=1.f/(8.f*F);
    launch_mconv<64,128,2,32,2,false,true ,false>(B2,nbr1,bwc1,         nullptr,nullptr,  nullptr,  nullptr,B0,PS(4),F,invN,stream);
    launch_mconv<128,128,2,32,2,true,true ,false>(B0,nbr1,bws1,         PS(4),bng1,      bnb1,     nullptr,B1,PS(5),F,invN,stream);
    launch_mconv<128,128,2,32,2,true,true ,false>(B1,nbr1,bws1+65536,   PS(5),bng1+128,  bnb1+128, nullptr,B2,PS(6),F,invN,stream);
    launch_mconv<128,128,2,32,2,true,true ,true >(B2,nbr1,bws1+131072,  PS(6),bng1+256,  bnb1+256, B0,     B1,PS(7),F,invN,stream);
    int n4p=8*6000*32; int gp=(n4p+255)/256; if (gp>2048) gp=2048;
    pool_kernel<<<gp,256,0,stream>>>(B1,pool1,PS(7),ng1,nb1,B0,32,F,6000,n4p,invN);
  }
  // -------- stage 2: F=6000, 128 -> 256 (CSPLIT=2: 1504 blocks of 128 thr) --------
  {
    const int F=6000; const float invN=1.f/(8.f*F);
    launch_mconv<128,256,2,64,1,false,true ,false>(B0,nbr2,bwc2,         nullptr,nullptr,  nullptr,  nullptr,B1,PS(8),F,invN,stream);
    launch_mconv<256,256,2,64,1,true,true ,false>(B1,nbr2,bws2,         PS(8), bng2,     bnb2,     nullptr,B2,PS(9),F,invN,stream);
    launch_mconv<256,256,2,64,1,true,true ,false>(B2,nbr2,bws2+262144,  PS(9), bng2+256, bnb2+256, nullptr,B0,PS(10),F,invN,stream);
    launch_mconv<256,256,2,64,1,true,true ,true >(B0,nbr2,bws2+524288,  PS(10),bng2+512, bnb2+512, B1,     B2,PS(11),F,invN,stream);
    int n4p=8*4000*64; int gp=(n4p+255)/256; if (gp>2048) gp=2048;
    pool_kernel<<<gp,256,0,stream>>>(B2,pool2,PS(11),ng2,nb2,B0,64,F,4000,n4p,invN);
    colsum_kernel<<<dim3(16,8),256,0,stream>>>(B0,bc,4000,250);
  }
  head_kernel<<<1,256,0,stream>>>(bc,fc1w,fc1b,fc2w,fc2b,outp,1.f/4000.f);
}

// Round 12
// 1088.554 us; speedup vs baseline: 1.1059x; 1.1059x over previous
//
#include <hip/hip_runtime.h>
#include <math.h>

#define NPART 64
#define TILE_F 16

typedef unsigned short u16;
typedef __attribute__((ext_vector_type(8))) short short8;
typedef __attribute__((ext_vector_type(4))) float f32x4;

__device__ __forceinline__ float relu_(float v){ return fmaxf(v, 0.f); }

__device__ __forceinline__ u16 f2bf(float x){
  unsigned u = __float_as_uint(x);
  u = (u + 0x7fffu + ((u >> 16) & 1u)) >> 16;
  return (u16)u;
}

static __device__ __forceinline__ f32x4 mfma_bf16(short8 a, short8 b, f32x4 c){
  asm("v_mfma_f32_16x16x32_bf16 %0, %1, %2, %0" : "+v"(c) : "v"(a), "v"(b));
  return c;
}

// ---------------------------------------------------------------------------
// MFMA mesh-conv (round-7/10 verified loop), KSTEP=64, B-slice prefetch,
// BN finalize folded into prologue, optional fused residual epilogue.
// Batch-per-XCD grid (r10: FETCH 111->72MB): batch = blockIdx.x & 7.
// WR=32 variant: BR=32 rows/block doubles grid (r7 lever: latency hiding via
// more independent blocks) without duplicating gather traffic. Threads with
// idx >= BR*4 skip gather/feature work (guarded).
//   out[r,o] = sum_k G[r,k] * W[o,k];  r = b*F+f, k = 4c+j
// ---------------------------------------------------------------------------
template<int CIN,int COUT,int WR,int NWR,bool BN,bool STATS,bool RES>
__global__ __launch_bounds__(NWR*(COUT/64)*64) void mconv_kernel(
    const float* __restrict__ xin, const int* __restrict__ nbr,
    const u16* __restrict__ wbf,
    const float* __restrict__ ps_in, const float* __restrict__ gamma,
    const float* __restrict__ beta, const float* __restrict__ res,
    float* __restrict__ out, float* __restrict__ psum,
    int F, float invN)
{
  constexpr int nWc = COUT/64;
  constexpr int T   = NWR*nWc*64;
  constexpr int BR  = NWR*WR;
  constexpr int K   = 4*CIN;
  constexpr int NSTEP = CIN/16;       // 16 channels (64 k) per step
  constexpr int GTOT  = BR*4;         // gather work items total
  constexpr int ITEMS = (GTOT + T - 1)/T;
  constexpr int NRF   = WR/16;        // row fragments per wave

  __shared__ __align__(16) u16 Gs[2][BR*64];
  __shared__ float ls[STATS?COUT:1], lq[STATS?COUT:1];
  __shared__ float aS[BN?CIN:1], dS[BN?CIN:1];

  const int t=threadIdx.x, lane=t&63, wid=t>>6;
  const int wm=wid/nWc, wc=wid%nWc;
  const int l15=lane&15, kq=lane>>4;

  const int batch = blockIdx.x & 7;       // XCD-locality: one batch per XCD
  const int row0  = (blockIdx.x >> 3) * BR;

  if (BN){
    for (int c=t;c<CIN;c+=T){
      float s=0.f,q=0.f;
      #pragma unroll 4
      for (int p=0;p<NPART;p++){ s+=ps_in[p*256+c]; q+=ps_in[(NPART+p)*256+c]; }
      float m=s*invN, v=q*invN-m*m;
      float ai=gamma[c]*rsqrtf(v+1e-5f);
      aS[c]=ai; dS[c]=beta[c]-m*ai;
    }
  }
  if (STATS){ for (int i=t;i<COUT;i+=T){ ls[i]=0.f; lq[i]=0.f; } }
  __syncthreads();

  // ---- gather pointers (fixed rows/channel-quads per thread) ----
  const float *P0[ITEMS],*P1[ITEMS],*P2[ITEMS],*P3[ITEMS];
  #pragma unroll
  for (int i=0;i<ITEMS;i++){
    int idx=i*T+t;
    if (idx<GTOT){
      int gr=idx>>2, c4q=idx&3;
      int f=row0+gr;
      if (f>=F) f=F-1;                    // clamp tail rows (outputs discarded)
      int i1=nbr[f*3+0], i2=nbr[f*3+1], i3=nbr[f*3+2];
      const float* xb=xin+(size_t)batch*F*CIN+c4q*4;
      P0[i]=xb+(size_t)f *CIN; P1[i]=xb+(size_t)i1*CIN;
      P2[i]=xb+(size_t)i2*CIN; P3[i]=xb+(size_t)i3*CIN;
    }
  }

  const u16* wp = wbf + (size_t)(wc*64+l15)*K + kq*8;
  auto BLD=[&](int cg,int j)->short8{
    return *(const short8*)(wp + (size_t)cg*16*K + (size_t)j*32);
  };
  auto ADS=[&](int pb,int rr,int h)->short8{
    int r=wm*WR+rr*16+l15;
    int sl=h*4+kq;
    return *(const short8*)&Gs[pb][(size_t)r*64 + (size_t)((sl^(r&7))*8)];
  };
  auto GLD=[&](int s,float4 (&g)[ITEMS][4]){
    #pragma unroll
    for (int i=0;i<ITEMS;i++){
      int idx=i*T+t;
      if (idx<GTOT){
        g[i][0]=*(const float4*)(P0[i]+s*16);
        g[i][1]=*(const float4*)(P1[i]+s*16);
        g[i][2]=*(const float4*)(P2[i]+s*16);
        g[i][3]=*(const float4*)(P3[i]+s*16);
      }
    }
  };
  auto BLDW=[&](int pb,int s,float4 (&g)[ITEMS][4]){
    #pragma unroll
    for (int i=0;i<ITEMS;i++){
      int idx=i*T+t;
      if (idx>=GTOT) continue;
      int gr=idx>>2, c4q=idx&3;
      float4 S=g[i][0],N1=g[i][1],N2=g[i][2],N3=g[i][3];
      if (BN){
        float4 a4=*(const float4*)&aS[s*16+c4q*4];
        float4 d4=*(const float4*)&dS[s*16+c4q*4];
        S.x =fmaf(relu_(S.x ),a4.x,d4.x); S.y =fmaf(relu_(S.y ),a4.y,d4.y);
        S.z =fmaf(relu_(S.z ),a4.z,d4.z); S.w =fmaf(relu_(S.w ),a4.w,d4.w);
        N1.x=fmaf(relu_(N1.x),a4.x,d4.x); N1.y=fmaf(relu_(N1.y),a4.y,d4.y);
        N1.z=fmaf(relu_(N1.z),a4.z,d4.z); N1.w=fmaf(relu_(N1.w),a4.w,d4.w);
        N2.x=fmaf(relu_(N2.x),a4.x,d4.x); N2.y=fmaf(relu_(N2.y),a4.y,d4.y);
        N2.z=fmaf(relu_(N2.z),a4.z,d4.z); N2.w=fmaf(relu_(N2.w),a4.w,d4.w);
        N3.x=fmaf(relu_(N3.x),a4.x,d4.x); N3.y=fmaf(relu_(N3.y),a4.y,d4.y);
        N3.z=fmaf(relu_(N3.z),a4.z,d4.z); N3.w=fmaf(relu_(N3.w),a4.w,d4.w);
      }
      short8 lo,hi;
      #define FEAT(dst,i0,sv,av,bv,cv) \
        dst[i0+0]=(short)f2bf(sv); \
        dst[i0+1]=(short)f2bf(av+bv+cv); \
        dst[i0+2]=(short)f2bf(fabsf(av-bv)+fabsf(bv-cv)+fabsf(cv-av)); \
        dst[i0+3]=(short)f2bf(fmaxf(fmaxf(av,bv),cv));
      FEAT(lo,0,S.x,N1.x,N2.x,N3.x)
      FEAT(lo,4,S.y,N1.y,N2.y,N3.y)
      FEAT(hi,0,S.z,N1.z,N2.z,N3.z)
      FEAT(hi,4,S.w,N1.w,N2.w,N3.w)
      #undef FEAT
      u16* rowp=&Gs[pb][(size_t)gr*64];
      *(short8*)&rowp[(size_t)(((2*c4q  )^(gr&7))*8)]=lo;
      *(short8*)&rowp[(size_t)(((2*c4q+1)^(gr&7))*8)]=hi;
    }
  };

  f32x4 acc[NRF][4];
  #pragma unroll
  for (int rr=0;rr<NRF;rr++)
    #pragma unroll
    for (int cg=0;cg<4;cg++){ f32x4 z={0.f,0.f,0.f,0.f}; acc[rr][cg]=z; }

  short8 B0[4],B1[4];
  #pragma unroll
  for (int cg=0;cg<4;cg++) B0[cg]=BLD(cg,0);
  #pragma unroll
  for (int cg=0;cg<4;cg++) B1[cg]=BLD(cg,1);

  { float4 g0[ITEMS][4]; GLD(0,g0); BLDW(0,0,g0); }
  __syncthreads();

  // round-7 verified single-step pipeline (2-deep regressed, r9)
  #pragma unroll 2
  for (int s=0;s<NSTEP;s++){
    const int pb=s&1;
    float4 g[ITEMS][4];
    if (s+1<NSTEP) GLD(s+1,g);               // issue gathers for next step
    short8 A[NRF];
    #pragma unroll
    for (int rr=0;rr<NRF;rr++) A[rr]=ADS(pb,rr,0);
    #pragma unroll
    for (int rr=0;rr<NRF;rr++)
      #pragma unroll
      for (int cg=0;cg<4;cg++) acc[rr][cg]=mfma_bf16(A[rr],B0[cg],acc[rr][cg]);
    if (s+1<NSTEP){
      #pragma unroll
      for (int cg=0;cg<4;cg++) B0[cg]=BLD(cg,2*(s+1));   // prefetch next slice
    }
    #pragma unroll
    for (int rr=0;rr<NRF;rr++) A[rr]=ADS(pb,rr,1);
    #pragma unroll
    for (int rr=0;rr<NRF;rr++)
      #pragma unroll
      for (int cg=0;cg<4;cg++) acc[rr][cg]=mfma_bf16(A[rr],B1[cg],acc[rr][cg]);
    if (s+1<NSTEP){
      #pragma unroll
      for (int cg=0;cg<4;cg++) B1[cg]=BLD(cg,2*(s+1)+1);
      BLDW(pb^1,s+1,g);                      // features -> other buffer
    }
    __syncthreads();
  }

  // ---- epilogue: (optional fused residual+relu) store + relu stats ----
  const size_t bbase=(size_t)batch*F;
  #pragma unroll
  for (int cg=0;cg<4;cg++){
    const int col=wc*64+cg*16+l15;
    float rs=0.f,rq=0.f;
    #pragma unroll
    for (int rr=0;rr<NRF;rr++){
      const int r0=row0 + wm*WR + rr*16 + kq*4;
      #pragma unroll
      for (int q=0;q<4;q++){
        int r=r0+q;
        if (r<F){
          size_t idx=(bbase+r)*COUT+col;
          float v=acc[rr][cg][q];
          if (RES){ v += res[idx]; v = relu_(v); }
          out[idx]=v;
          if (STATS){ float rv = RES ? v : relu_(v); rs+=rv; rq+=rv*rv; }
        }
      }
    }
    if (STATS){ atomicAdd(&ls[col],rs); atomicAdd(&lq[col],rq); }
  }
  if (STATS){
    __syncthreads();
    const int part=blockIdx.x&(NPART-1);
    for (int i=t;i<COUT;i+=T){
      atomicAdd(&psum[(size_t)part*256+i],ls[i]);
      atomicAdd(&psum[(size_t)(NPART+part)*256+i],lq[i]);
    }
  }
}

// ---------------------------------------------------------------------------
// fp32 conv path (tiny 9->64 conv only)
// ---------------------------------------------------------------------------
template<int CIN,int COUT,bool BN,bool STATS>
__global__ __launch_bounds__(256) void conv_kernel(
    const float* __restrict__ xin, const int* __restrict__ nbr,
    const float* __restrict__ Wt, const float* __restrict__ bn_a,
    const float* __restrict__ bn_d,
    float* __restrict__ out, float* __restrict__ psum, int F)
{
  constexpr int K = 4*CIN;
  constexpr int ROWLEN = K + 4;
  __shared__ float Gs[TILE_F][ROWLEN];
  __shared__ int   nI[TILE_F*3];
  __shared__ float ls[STATS?COUT:1];
  __shared__ float lq[STATS?COUT:1];
  const int t = threadIdx.x;
  const int fbase = blockIdx.x*TILE_F;
  const int b = blockIdx.y;
  const float* __restrict__ xb = xin + (size_t)b*F*CIN;

  if (t < TILE_F*3){ int fi=t/3, j=t-fi*3; int fg=fbase+fi; nI[t]=(fg<F)?nbr[fg*3+j]:0; }
  if (STATS){ for (int i=t;i<COUT;i+=256){ ls[i]=0.f; lq[i]=0.f; } }
  __syncthreads();

  for (int idx=t; idx<TILE_F*CIN; idx+=256){
    int fi=idx/CIN, c=idx-fi*CIN;
    int fg=fbase+fi;
    float* dst=&Gs[fi][4*c];
    if (fg<F){
      int i1=nI[fi*3], i2=nI[fi*3+1], i3=nI[fi*3+2];
      float s =xb[(size_t)fg*CIN+c];
      float v1=xb[(size_t)i1*CIN+c];
      float v2=xb[(size_t)i2*CIN+c];
      float v3=xb[(size_t)i3*CIN+c];
      if (BN){ float a=bn_a[c], dd=bn_d[c];
        s=fmaf(relu_(s),a,dd); v1=fmaf(relu_(v1),a,dd);
        v2=fmaf(relu_(v2),a,dd); v3=fmaf(relu_(v3),a,dd); }
      dst[0]=s; dst[1]=v1+v2+v3;
      dst[2]=fabsf(v1-v2)+fabsf(v2-v3)+fabsf(v3-v1);
      dst[3]=fmaxf(fmaxf(v1,v2),v3);
    } else { dst[0]=0.f;dst[1]=0.f;dst[2]=0.f;dst[3]=0.f; }
  }
  __syncthreads();

  constexpr int OQ=COUT/4;
  constexpr int R=256/OQ;
  constexpr int FPT=TILE_F/R;
  const int col=t%OQ, row=t/OQ;
  const int o0=col*4, f0=row*FPT;
  float4 acc[FPT];
  #pragma unroll
  for (int fi=0;fi<FPT;fi++){ acc[fi].x=0.f;acc[fi].y=0.f;acc[fi].z=0.f;acc[fi].w=0.f; }

  for (int k=0;k<K;k+=4){
    float4 w0=*(const float4*)&Wt[(size_t)(k+0)*COUT+o0];
    float4 w1=*(const float4*)&Wt[(size_t)(k+1)*COUT+o0];
    float4 w2=*(const float4*)&Wt[(size_t)(k+2)*COUT+o0];
    float4 w3=*(const float4*)&Wt[(size_t)(k+3)*COUT+o0];
    #pragma unroll
    for (int fi=0;fi<FPT;fi++){
      float4 g=*(const float4*)&Gs[f0+fi][k];
      acc[fi].x=fmaf(g.x,w0.x,fmaf(g.y,w1.x,fmaf(g.z,w2.x,fmaf(g.w,w3.x,acc[fi].x))));
      acc[fi].y=fmaf(g.x,w0.y,fmaf(g.y,w1.y,fmaf(g.z,w2.y,fmaf(g.w,w3.y,acc[fi].y))));
      acc[fi].z=fmaf(g.x,w0.z,fmaf(g.y,w1.z,fmaf(g.z,w2.z,fmaf(g.w,w3.z,acc[fi].z))));
      acc[fi].w=fmaf(g.x,w0.w,fmaf(g.y,w1.w,fmaf(g.z,w2.w,fmaf(g.w,w3.w,acc[fi].w))));
    }
  }

  float4 rs={0,0,0,0}, rq={0,0,0,0};
  #pragma unroll
  for (int fi=0;fi<FPT;fi++){
    int fg=fbase+f0+fi;
    if (fg<F){
      *(float4*)&out[((size_t)b*F+fg)*COUT+o0]=acc[fi];
      if (STATS){
        float rx=relu_(acc[fi].x), ry=relu_(acc[fi].y);
        float rz=relu_(acc[fi].z), rw=relu_(acc[fi].w);
        rs.x+=rx; rs.y+=ry; rs.z+=rz; rs.w+=rw;
        rq.x+=rx*rx; rq.y+=ry*ry; rq.z+=rz*rz; rq.w+=rw*rw;
      }
    }
  }
  if (STATS){
    atomicAdd(&ls[o0+0],rs.x); atomicAdd(&ls[o0+1],rs.y);
    atomicAdd(&ls[o0+2],rs.z); atomicAdd(&ls[o0+3],rs.w);
    atomicAdd(&lq[o0+0],rq.x); atomicAdd(&lq[o0+1],rq.y);
    atomicAdd(&lq[o0+2],rq.z); atomicAdd(&lq[o0+3],rq.w);
    __syncthreads();
    int part=(blockIdx.y*gridDim.x+blockIdx.x)&(NPART-1);
    for (int i=t;i<COUT;i+=256){
      atomicAdd(&psum[(size_t)part*256+i], ls[i]);
      atomicAdd(&psum[(size_t)(NPART+part)*256+i], lq[i]);
    }
  }
}

// pool with folded BN finalize: aS/dS computed from psum partials per block
__global__ __launch_bounds__(256) void pool_kernel(
    const float* __restrict__ z, const int* __restrict__ pl,
    const float* __restrict__ ps_in, const float* __restrict__ gamma,
    const float* __restrict__ beta,
    float* __restrict__ out, int C4, int F, int Fn, int n4, float invN)
{
  __shared__ float aS[256], dS[256];
  const int C=C4*4;
  const int t=threadIdx.x;
  if (t<C){
    float s=0.f,q=0.f;
    #pragma unroll 4
    for (int p=0;p<NPART;p++){ s+=ps_in[p*256+t]; q+=ps_in[(NPART+p)*256+t]; }
    float m=s*invN, v=q*invN-m*m;
    float ai=gamma[t]*rsqrtf(v+1e-5f);
    aS[t]=ai; dS[t]=beta[t]-m*ai;
  }
  __syncthreads();
  for (int i=blockIdx.x*256+t; i<n4; i+=gridDim.x*256){
    int c4=i%C4; int rest=i/C4; int p=rest%Fn; int b=rest/Fn;
    int p0=pl[p*3], p1=pl[p*3+1], p2=pl[p*3+2];
    float4 a4=*(const float4*)&aS[4*c4], d4=*(const float4*)&dS[4*c4];
    float4 v0=*(const float4*)&z[((size_t)b*F+p0)*C+4*c4];
    float4 v1=*(const float4*)&z[((size_t)b*F+p1)*C+4*c4];
    float4 v2=*(const float4*)&z[((size_t)b*F+p2)*C+4*c4];
    float4 r;
    r.x=(relu_(fmaf(v0.x,a4.x,d4.x))+relu_(fmaf(v1.x,a4.x,d4.x))+relu_(fmaf(v2.x,a4.x,d4.x)))*(1.f/3.f);
    r.y=(relu_(fmaf(v0.y,a4.y,d4.y))+relu_(fmaf(v1.y,a4.y,d4.y))+relu_(fmaf(v2.y,a4.y,d4.y)))*(1.f/3.f);
    r.z=(relu_(fmaf(v0.z,a4.z,d4.z))+relu_(fmaf(v1.z,a4.z,d4.z))+relu_(fmaf(v2.z,a4.z,d4.z)))*(1.f/3.f);
    r.w=(relu_(fmaf(v0.w,a4.w,d4.w))+relu_(fmaf(v1.w,a4.w,d4.w))+relu_(fmaf(v2.w,a4.w,d4.w)))*(1.f/3.f);
    *(float4*)&out[((size_t)b*Fn+p)*C+4*c4]=r;
  }
}

__global__ __launch_bounds__(256) void colsum_kernel(
    const float* __restrict__ x, float* __restrict__ bc, int F, int chunk)
{
  int b=blockIdx.y; int f0=blockIdx.x*chunk;
  int c=threadIdx.x;
  int fe=f0+chunk; if (fe>F) fe=F;
  float s=0.f;
  for (int f=f0;f<fe;f++) s+=x[((size_t)b*F+f)*256+c];
  atomicAdd(&bc[b*256+c], s);
}

__global__ __launch_bounds__(256) void head_kernel(
    const float* __restrict__ bc, const float* __restrict__ w1,
    const float* __restrict__ b1, const float* __restrict__ w2,
    const float* __restrict__ b2, float* __restrict__ outp, float invF)
{
  __shared__ float xm[8*256];
  __shared__ float h[8*128];
  int t=threadIdx.x;
  for (int i=t;i<2048;i+=256) xm[i]=bc[i]*invF;
  __syncthreads();
  #pragma unroll
  for (int r=0;r<4;r++){
    int idx=t+r*256; int b=idx>>7, j=idx&127;
    float s=b1[j];
    for (int c=0;c<256;c++) s=fmaf(xm[b*256+c],w1[j*256+c],s);
    h[idx]=relu_(s);
  }
  __syncthreads();
  if (t<8){
    float s=b2[0];
    for (int j=0;j<128;j++) s=fmaf(h[t*128+j],w2[j],s);
    outp[t]=1.f/(1.f+expf(-s));
  }
}

__global__ __launch_bounds__(256) void transpose_in_kernel(
    const float* __restrict__ x, float* __restrict__ xt, int F)
{
  int i=blockIdx.x*256+threadIdx.x;
  int total=8*9*F;
  if (i<total){ int f=i%F; int c=(i/F)%9; int b=i/(9*F);
    xt[((size_t)b*F+f)*9+c]=x[i]; }
}

__global__ __launch_bounds__(256) void transpose_w_kernel(
    const float* __restrict__ w, float* __restrict__ wt, int K, int COUT)
{
  int i=blockIdx.x*256+threadIdx.x;
  if (i<K*COUT){ int o=i/K, k=i-o*K; wt[(size_t)k*COUT+o]=w[i]; }
}

__global__ __launch_bounds__(256) void cvt_bf16_kernel(
    const float* __restrict__ w, u16* __restrict__ o, int n)
{
  int i=blockIdx.x*256+threadIdx.x;
  if (i<n) o[i]=f2bf(w[i]);
}

// ---------------------------------------------------------------------------

template<int CIN,int COUT,int WR,int NWR,bool BN,bool STATS,bool RES>
static void launch_mconv(const float* xin, const int* nbr, const u16* wbf,
                         const float* ps_in, const float* gamma, const float* beta,
                         const float* res, float* out, float* ps_out,
                         int F, float invN, hipStream_t stream)
{
  constexpr int T  = NWR*(COUT/64)*64;
  constexpr int BR = NWR*WR;
  int nb = (F + BR - 1)/BR;
  mconv_kernel<CIN,COUT,WR,NWR,BN,STATS,RES><<<8*nb, T, 0, stream>>>(
      xin,nbr,wbf,ps_in,gamma,beta,res,out,ps_out,F,invN);
}

extern "C" void kernel_launch(void* const* d_in, const int* in_sizes, int n_in,
                              void* d_out, int out_size, void* d_ws, size_t ws_size,
                              hipStream_t stream)
{
  const float* x    =(const float*)d_in[0];
  const int*  nbr0  =(const int*)d_in[1];
  const int*  pool0 =(const int*)d_in[2];
  const int*  nbr1  =(const int*)d_in[3];
  const int*  pool1 =(const int*)d_in[4];
  const int*  nbr2  =(const int*)d_in[5];
  const int*  pool2 =(const int*)d_in[6];
  const float* wc0  =(const float*)d_in[7];
  const float* ws0  =(const float*)d_in[8];
  const float* bng0 =(const float*)d_in[9];
  const float* bnb0 =(const float*)d_in[10];
  const float* ng0  =(const float*)d_in[11];
  const float* nb0  =(const float*)d_in[12];
  const float* wc1  =(const float*)d_in[13];
  const float* ws1  =(const float*)d_in[14];
  const float* bng1 =(const float*)d_in[15];
  const float* bnb1 =(const float*)d_in[16];
  const float* ng1  =(const float*)d_in[17];
  const float* nb1  =(const float*)d_in[18];
  const float* wc2  =(const float*)d_in[19];
  const float* ws2  =(const float*)d_in[20];
  const float* bng2 =(const float*)d_in[21];
  const float* bnb2 =(const float*)d_in[22];
  const float* ng2  =(const float*)d_in[23];
  const float* nb2  =(const float*)d_in[24];
  const float* fc1w =(const float*)d_in[25];
  const float* fc1b =(const float*)d_in[26];
  const float* fc2w =(const float*)d_in[27];
  const float* fc2b =(const float*)d_in[28];
  float* outp=(float*)d_out;

  char* base=(char*)d_ws;
  size_t off=0;
  auto alloc=[&](size_t nbytes)->void*{
    void* p=base+off; off=(off+nbytes+255)&~(size_t)255; return p; };

  float* psum0 =(float*)alloc((size_t)12*131072);
  float* bc    =(float*)alloc(8192);
  float* wt_wc0=(float*)alloc((size_t)36*64*4);
  u16*   bws0  =(u16*)alloc((size_t)3*16384*2);
  u16*   bwc1  =(u16*)alloc((size_t)32768*2);
  u16*   bws1  =(u16*)alloc((size_t)3*65536*2);
  u16*   bwc2  =(u16*)alloc((size_t)131072*2);
  u16*   bws2  =(u16*)alloc((size_t)3*262144*2);
  float* xT    =(float*)alloc((size_t)8*12000*9*4);
  float* B0    =(float*)alloc((size_t)49152000);
  float* B1    =(float*)alloc((size_t)49152000);
  float* B2    =(float*)alloc((size_t)49152000);
  if (off>ws_size) return;

  auto PS=[&](int i){ return psum0+(size_t)i*32768; };

  hipMemsetAsync(psum0,0,(size_t)12*131072+8192,stream);

  { int n=8*9*12000; transpose_in_kernel<<<(n+255)/256,256,0,stream>>>(x,xT,12000); }
  { int n=36*64; transpose_w_kernel<<<(n+255)/256,256,0,stream>>>(wc0,wt_wc0,36,64); }
  auto cv=[&](const float* w,u16* o,int n){
    cvt_bf16_kernel<<<(n+255)/256,256,0,stream>>>(w,o,n); };
  cv(ws0,bws0,3*16384);
  cv(wc1,bwc1,32768);
  cv(ws1,bws1,3*65536);
  cv(wc2,bwc2,131072);
  cv(ws2,bws2,3*262144);

  // -------- stage 0: F=12000, 9 -> 64 --------
  {
    const int F=12000; const float invN=1.f/(8.f*F);
    dim3 grid((F+TILE_F-1)/TILE_F, 8);
    conv_kernel<9,64,false,true><<<grid,256,0,stream>>>(xT,nbr0,wt_wc0,nullptr,nullptr,B0,PS(0),F);
    launch_mconv<64,64,32,2,true,true ,false>(B0,nbr0,bws0,        PS(0),bng0,     bnb0,     nullptr,B1,PS(1),F,invN,stream);
    launch_mconv<64,64,32,2,true,true ,false>(B1,nbr0,bws0+16384,  PS(1),bng0+64,  bnb0+64,  nullptr,B2,PS(2),F,invN,stream);
    // 4th conv: fused residual relu(y + B0) + stats for the outer BN (PS(3))
    launch_mconv<64,64,32,2,true,true ,true >(B2,nbr0,bws0+32768,  PS(2),bng0+128, bnb0+128, B0,     B1,PS(3),F,invN,stream);
    int n4p=8*9000*16; int gp=(n4p+255)/256; if (gp>2048) gp=2048;
    pool_kernel<<<gp,256,0,stream>>>(B1,pool0,PS(3),ng0,nb0,B2,16,F,9000,n4p,invN);
  }
  // -------- stage 1: F=9000, 64 -> 128 --------
  {
    const int F=9000; const float invN=1.f/(8.f*F);
    launch_mconv<64,128,64,1,false,true ,false>(B2,nbr1,bwc1,         nullptr,nullptr,  nullptr,  nullptr,B0,PS(4),F,invN,stream);
    launch_mconv<128,128,64,1,true,true ,false>(B0,nbr1,bws1,         PS(4),bng1,      bnb1,     nullptr,B1,PS(5),F,invN,stream);
    launch_mconv<128,128,64,1,true,true ,false>(B1,nbr1,bws1+65536,   PS(5),bng1+128,  bnb1+128, nullptr,B2,PS(6),F,invN,stream);
    launch_mconv<128,128,64,1,true,true ,true >(B2,nbr1,bws1+131072,  PS(6),bng1+256,  bnb1+256, B0,     B1,PS(7),F,invN,stream);
    int n4p=8*6000*32; int gp=(n4p+255)/256; if (gp>2048) gp=2048;
    pool_kernel<<<gp,256,0,stream>>>(B1,pool1,PS(7),ng1,nb1,B0,32,F,6000,n4p,invN);
  }
  // -------- stage 2: F=6000, 128 -> 256, WR=32: BR=32, grid 1504x256thr --------
  {
    const int F=6000; const float invN=1.f/(8.f*F);
    launch_mconv<128,256,32,1,false,true ,false>(B0,nbr2,bwc2,         nullptr,nullptr,  nullptr,  nullptr,B1,PS(8),F,invN,stream);
    launch_mconv<256,256,32,1,true,true ,false>(B1,nbr2,bws2,         PS(8), bng2,     bnb2,     nullptr,B2,PS(9),F,invN,stream);
    launch_mconv<256,256,32,1,true,true ,false>(B2,nbr2,bws2+262144,  PS(9), bng2+256, bnb2+256, nullptr,B0,PS(10),F,invN,stream);
    launch_mconv<256,256,32,1,true,true ,true >(B0,nbr2,bws2+524288,  PS(10),bng2+512, bnb2+512, B1,     B2,PS(11),F,invN,stream);
    int n4p=8*4000*64; int gp=(n4p+255)/256; if (gp>2048) gp=2048;
    pool_kernel<<<gp,256,0,stream>>>(B2,pool2,PS(11),ng2,nb2,B0,64,F,4000,n4p,invN);
    colsum_kernel<<<dim3(16,8),256,0,stream>>>(B0,bc,4000,250);
  }
  head_kernel<<<1,256,0,stream>>>(bc,fc1w,fc1b,fc2w,fc2b,outp,1.f/4000.f);
}